// Round 5
// baseline (303.977 us; speedup 1.0000x reference)
//
#include <hip/hip_runtime.h>
#include <hip/hip_bf16.h>

// Simple_6270652252303. Inputs are float32 (R3 bf16-hard-code NaN'd; R2/R4 pass
// via detector choosing f32). Detector kept as insurance. Text branch only.
//   K1 k_text: text -> {delta, delta*x}, Bm, Cm. 1 row/wave, wave-private LDS,
//              NO barriers, deep unroll for load ILP.
//   K2 k_scan: S6 scan -> y. Wave per 2 d's, lanes over N, depth-2 register
//              prefetch, no LDS/barriers.
//   K3 k_head: y @ cW1+cb1 @ cW2+cb2 -> out. Wave per row, no barriers.

typedef __hip_bfloat16 bf16;

#define BATCH 64
#define SEQ   63
#define ROWS  (BATCH * SEQ)   // 4032
#define DIN   100
#define H1    128
#define DM    100
#define NS    300

__device__ __forceinline__ float2 up2(unsigned u) {
    float2 r;
    r.x = __uint_as_float(u << 16);
    r.y = __uint_as_float(u & 0xffff0000u);
    return r;
}
template<bool ISB>
__device__ __forceinline__ float LD(const void* p, int i) {
    if (ISB) return __bfloat162float(((const bf16*)p)[i]);
    else     return ((const float*)p)[i];
}
template<bool ISB>
__device__ __forceinline__ float2 LD2(const void* p, int i) {   // elements 2i,2i+1
    if (ISB) return up2(((const unsigned*)p)[i]);
    else     return ((const float2*)p)[i];
}
__device__ __forceinline__ float waveReduceSum(float v) {
#pragma unroll
    for (int off = 32; off > 0; off >>= 1) v += __shfl_xor(v, off, 64);
    return v;
}
__device__ __forceinline__ float lrelu(float x) { return x >= 0.f ? x : 0.01f * x; }
__device__ __forceinline__ float softplusf(float x) {
    return (x > 20.f) ? x : log1pf(__expf(x));
}

// bf16-vs-f32 storage detector (wave-uniform via ballot; no LDS, no barrier).
__device__ __forceinline__ bool detect_bf16(const unsigned short* __restrict__ probe) {
    const int l = threadIdx.x & 63;
    const unsigned u0 = probe[l * 2];
    const unsigned u1 = probe[l * 2 + 1];
    const float v0 = fabsf(__uint_as_float(u0 << 16));
    const float v1 = fabsf(__uint_as_float(u1 << 16));
    const bool big = !(v0 < 1000.f) || !(v1 < 1000.f);  // NaN-safe
    const bool zero_even = (u0 == 0u);
    const unsigned long long mb = __ballot(big);
    const unsigned long long mz = __ballot(zero_even);
    return (mb == 0ULL) && (__popcll(mz) < 32);
}

// ---------------------------------------------------------------------------
// K1: fused text branch. 1 row per wave, 4 waves/block, wave-private LDS.
// ---------------------------------------------------------------------------
template<bool ISB>
__device__ __forceinline__ void text_impl(
    const void* __restrict__ text,
    const void* __restrict__ tW1, const void* __restrict__ tb1,
    const void* __restrict__ tg1, const void* __restrict__ tbe1,
    const void* __restrict__ tW2, const void* __restrict__ tb2,
    const void* __restrict__ tg2, const void* __restrict__ tbe2,
    const void* __restrict__ sW1, const void* __restrict__ sb1,
    const void* __restrict__ sW2, const void* __restrict__ sb2,
    const void* __restrict__ sW3, const void* __restrict__ sb3,
    float* __restrict__ ddx, float* __restrict__ Bmo, float* __restrict__ Cmo,
    float (&xb)[4][100], float (&t1b)[4][128], float (&t2b)[4][100])
{
    const int w    = threadIdx.x >> 6;
    const int lane = threadIdx.x & 63;
    const int row  = blockIdx.x * 4 + w;       // grid 1008 -> 4032 rows

    if (lane < 50) {                           // stage x row (wave-private)
        const float2 xv = LD2<ISB>(text, row * 50 + lane);
        xb[w][2 * lane]     = xv.x;
        xb[w][2 * lane + 1] = xv.y;
    }
    // no barrier: same wave writes & reads xb[w]

    // ---- GEMM1 (100 -> 128): lane covers cols 2*lane, 2*lane+1 ----
    const float2 b1v = LD2<ISB>(tb1, lane);
    float ax = b1v.x, ay = b1v.y;
#pragma unroll 8
    for (int k = 0; k < DIN; ++k) {
        const float2 wv = LD2<ISB>(tW1, k * 64 + lane);
        const float xv = xb[w][k];
        ax += xv * wv.x; ay += xv * wv.y;
    }
    {   // LN(128) + LReLU
        const float sm = waveReduceSum(ax + ay);
        const float sq = waveReduceSum(ax * ax + ay * ay);
        const float m  = sm * (1.f / 128.f);
        const float rs = rsqrtf(sq * (1.f / 128.f) - m * m + 1e-5f);
        const float2 g = LD2<ISB>(tg1, lane), be = LD2<ISB>(tbe1, lane);
        t1b[w][2 * lane]     = lrelu((ax - m) * rs * g.x + be.x);
        t1b[w][2 * lane + 1] = lrelu((ay - m) * rs * g.y + be.y);
    }

    // ---- GEMM2 (128 -> 100): lanes 0..49 cover cols 2li, 2li+1 ----
    const bool act = lane < 50;
    const int  li  = act ? lane : 0;
    const float2 b2v = LD2<ISB>(tb2, li);
    float cx = b2v.x, cy = b2v.y;
#pragma unroll 8
    for (int k = 0; k < H1; ++k) {
        const float2 wv = LD2<ISB>(tW2, k * 50 + li);
        const float tv = t1b[w][k];
        cx += tv * wv.x; cy += tv * wv.y;
    }
    {   // LN(100) + LReLU
        const float sm = waveReduceSum(act ? cx + cy : 0.f);
        const float sq = waveReduceSum(act ? cx * cx + cy * cy : 0.f);
        const float m  = sm * 0.01f;
        const float rs = rsqrtf(sq * 0.01f - m * m + 1e-5f);
        if (act) {
            const float2 g = LD2<ISB>(tg2, lane), be = LD2<ISB>(tbe2, lane);
            t2b[w][2 * lane]     = lrelu((cx - m) * rs * g.x + be.x);
            t2b[w][2 * lane + 1] = lrelu((cy - m) * rs * g.y + be.y);
        }
    }

    // ---- fused delta(100) + Bm(300) + Cm(300) over k < 100 ----
    const float2 sbv = LD2<ISB>(sb1, li);
    float dlx = sbv.x, dly = sbv.y;
    int pc[3]; bool pv[3];
    float2 aB[3], aC[3];
#pragma unroll
    for (int cc = 0; cc < 3; ++cc) {
        const int p = lane + 64 * cc;
        pv[cc] = p < 150;
        pc[cc] = pv[cc] ? p : 0;
        aB[cc] = LD2<ISB>(sb2, pc[cc]);
        aC[cc] = LD2<ISB>(sb3, pc[cc]);
    }
#pragma unroll 4
    for (int k = 0; k < DM; ++k) {
        const float tv = t2b[w][k];
        const float2 wv = LD2<ISB>(sW1, k * 50 + li);
        dlx += tv * wv.x; dly += tv * wv.y;
#pragma unroll
        for (int cc = 0; cc < 3; ++cc) {
            const float2 bw = LD2<ISB>(sW2, k * 150 + pc[cc]);
            const float2 cw = LD2<ISB>(sW3, k * 150 + pc[cc]);
            aB[cc].x += tv * bw.x; aB[cc].y += tv * bw.y;
            aC[cc].x += tv * cw.x; aC[cc].y += tv * cw.y;
        }
    }
    if (act) {
        const float de0 = softplusf(dlx);
        const float de1 = softplusf(dly);
        float4 o;
        o.x = de0; o.y = de0 * t2b[w][2 * lane];
        o.z = de1; o.w = de1 * t2b[w][2 * lane + 1];
        *(float4*)(ddx + row * (2 * DM) + 4 * lane) = o;
    }
#pragma unroll
    for (int cc = 0; cc < 3; ++cc) {
        if (pv[cc]) {
            *(float2*)(Bmo + row * NS + 2 * pc[cc]) = aB[cc];
            *(float2*)(Cmo + row * NS + 2 * pc[cc]) = aC[cc];
        }
    }
}

__global__ __launch_bounds__(256) void k_text(
    const void* text,
    const void* tW1, const void* tb1, const void* tg1, const void* tbe1,
    const void* tW2, const void* tb2, const void* tg2, const void* tbe2,
    const void* sW1, const void* sb1, const void* sW2, const void* sb2,
    const void* sW3, const void* sb3,
    float* ddx, float* Bmo, float* Cmo, const unsigned short* probe)
{
    __shared__ float xb[4][100];
    __shared__ float t1b[4][128];
    __shared__ float t2b[4][100];
    if (detect_bf16(probe))
        text_impl<true >(text, tW1, tb1, tg1, tbe1, tW2, tb2, tg2, tbe2,
                         sW1, sb1, sW2, sb2, sW3, sb3, ddx, Bmo, Cmo, xb, t1b, t2b);
    else
        text_impl<false>(text, tW1, tb1, tg1, tbe1, tW2, tb2, tg2, tbe2,
                         sW1, sb1, sW2, sb2, sW3, sb3, ddx, Bmo, Cmo, xb, t1b, t2b);
}

// ---------------------------------------------------------------------------
// K2: S6 scan. Wave wid: b=wid/50, d-pair dp=wid%50. Depth-2 prefetch.
// ---------------------------------------------------------------------------
template<bool ISB>
__device__ __forceinline__ void scan_impl(
    const float* __restrict__ ddx, const float* __restrict__ Bm,
    const float* __restrict__ Cm, const void* __restrict__ sA,
    float* __restrict__ y)
{
    const int w    = threadIdx.x >> 6;
    const int lane = threadIdx.x & 63;
    const int wid  = blockIdx.x * 4 + w;      // 0..3199
    const int b    = wid / 50;
    const int dp   = wid % 50;
    const int d0   = 2 * dp, d1 = d0 + 1;

    int nc[5]; bool nv[5];
    float A0[5], A1[5], h0[5], h1[5];
#pragma unroll
    for (int c = 0; c < 5; ++c) {
        const int n = lane + 64 * c;
        nv[c] = n < NS;
        nc[c] = nv[c] ? n : 0;
        A0[c] = nv[c] ? LD<ISB>(sA, d0 * NS + nc[c]) : 0.f;
        A1[c] = nv[c] ? LD<ISB>(sA, d1 * NS + nc[c]) : 0.f;
        h0[c] = 0.f; h1[c] = 0.f;
    }

    const float* ddp = ddx + (b * SEQ) * (2 * DM) + 4 * dp;  // {de0,dx0,de1,dx1}
    const float* Bp  = Bm  + (b * SEQ) * NS;
    const float* Cp  = Cm  + (b * SEQ) * NS;
    float*       yp  = y   + (b * SEQ) * DM + d0;

    // prime l=0 (cur) and l=1 (nxt)
    float4 dd0 = *(const float4*)ddp;
    float4 dd1 = *(const float4*)(ddp + 1 * (2 * DM));
    float b0[5], c0[5], b1[5], c1[5];
#pragma unroll
    for (int c = 0; c < 5; ++c) {
        b0[c] = nv[c] ? Bp[nc[c]] : 0.f;
        c0[c] = nv[c] ? Cp[nc[c]] : 0.f;
        b1[c] = nv[c] ? Bp[NS + nc[c]] : 0.f;
        c1[c] = nv[c] ? Cp[NS + nc[c]] : 0.f;
    }

    for (int l = 0; l < SEQ; ++l) {
        float4 dd2 = dd1;
        float b2[5], c2[5];
#pragma unroll
        for (int c = 0; c < 5; ++c) { b2[c] = b1[c]; c2[c] = c1[c]; }
        if (l + 2 < SEQ) {                     // prefetch two steps ahead
            dd2 = *(const float4*)(ddp + (l + 2) * (2 * DM));
#pragma unroll
            for (int c = 0; c < 5; ++c) {
                b2[c] = nv[c] ? Bp[(l + 2) * NS + nc[c]] : 0.f;
                c2[c] = nv[c] ? Cp[(l + 2) * NS + nc[c]] : 0.f;
            }
        }
        float acc0 = 0.f, acc1 = 0.f;
#pragma unroll
        for (int c = 0; c < 5; ++c) {
            h0[c] = __expf(dd0.x * A0[c]) * h0[c] + dd0.y * b0[c];
            acc0 += c0[c] * h0[c];
            h1[c] = __expf(dd0.z * A1[c]) * h1[c] + dd0.w * b0[c];
            acc1 += c0[c] * h1[c];
        }
        acc0 = waveReduceSum(acc0);
        acc1 = waveReduceSum(acc1);
        if (lane == 0) *(float2*)(yp + l * DM) = make_float2(acc0, acc1);
        dd0 = dd1; dd1 = dd2;
#pragma unroll
        for (int c = 0; c < 5; ++c) {
            b0[c] = b1[c]; c0[c] = c1[c];
            b1[c] = b2[c]; c1[c] = c2[c];
        }
    }
}

__global__ __launch_bounds__(256) void k_scan(
    const float* ddx, const float* Bm, const float* Cm,
    const void* sA, float* y, const unsigned short* probe)
{
    if (detect_bf16(probe)) scan_impl<true >(ddx, Bm, Cm, sA, y);
    else                    scan_impl<false>(ddx, Bm, Cm, sA, y);
}

// ---------------------------------------------------------------------------
// K3: head. Wave per row, wave-private LDS, no barriers.
// ---------------------------------------------------------------------------
template<bool ISB>
__device__ __forceinline__ void head_impl(
    const float* __restrict__ y,
    const void* __restrict__ cW1, const void* __restrict__ cb1,
    const void* __restrict__ cW2, const void* __restrict__ cb2,
    void* __restrict__ outp, float (&ybuf)[4][100])
{
    const int w    = threadIdx.x >> 6;
    const int lane = threadIdx.x & 63;
    const int row  = blockIdx.x * 4 + w;

    ybuf[w][lane] = y[row * DM + lane];
    if (lane < DM - 64) ybuf[w][lane + 64] = y[row * DM + lane + 64];
    // no barrier: wave-private

    const bool vi = lane < 50;
    const int  i  = vi ? lane : 0;
    float o1 = LD<ISB>(cb1, i);
#pragma unroll 10
    for (int k = 0; k < DM; ++k) o1 += ybuf[w][k] * LD<ISB>(cW1, k * 50 + i);

    float p0 = vi ? o1 * LD<ISB>(cW2, i * 2 + 0) : 0.f;
    float p1 = vi ? o1 * LD<ISB>(cW2, i * 2 + 1) : 0.f;
    p0 = waveReduceSum(p0);
    p1 = waveReduceSum(p1);
    if (lane == 0) {
        const float r0 = p0 + LD<ISB>(cb2, 0);
        const float r1 = p1 + LD<ISB>(cb2, 1);
        if (ISB) {
            ((bf16*)outp)[row * 2 + 0] = __float2bfloat16(r0);
            ((bf16*)outp)[row * 2 + 1] = __float2bfloat16(r1);
        } else {
            *(float2*)((float*)outp + row * 2) = make_float2(r0, r1);
        }
    }
}

__global__ __launch_bounds__(256) void k_head(
    const float* y, const void* cW1, const void* cb1,
    const void* cW2, const void* cb2, void* outp, const unsigned short* probe)
{
    __shared__ float ybuf[4][100];
    if (detect_bf16(probe)) head_impl<true >(y, cW1, cb1, cW2, cb2, outp, ybuf);
    else                    head_impl<false>(y, cW1, cb1, cW2, cb2, outp, ybuf);
}

// ---------------------------------------------------------------------------
extern "C" void kernel_launch(void* const* d_in, const int* in_sizes, int n_in,
                              void* d_out, int out_size, void* d_ws, size_t ws_size,
                              hipStream_t stream)
{
    const void* text = d_in[0];
    const void* tW1  = d_in[3];
    const void* tb1  = d_in[4];
    const void* tg1  = d_in[5];
    const void* tbe1 = d_in[6];
    const void* tW2  = d_in[7];
    const void* tb2  = d_in[8];
    const void* tg2  = d_in[9];
    const void* tbe2 = d_in[10];
    const void* sW1  = d_in[11];
    const void* sb1  = d_in[12];
    const void* sW2  = d_in[13];
    const void* sb2  = d_in[14];
    const void* sW3  = d_in[15];
    const void* sb3  = d_in[16];
    const void* sA   = d_in[17];
    const void* cW1  = d_in[34];
    const void* cb1  = d_in[35];
    const void* cW2  = d_in[36];
    const void* cb2  = d_in[37];
    const unsigned short* probe = (const unsigned short*)d_in[3];

    float* ws  = (float*)d_ws;
    float* ddx = ws;                          // ROWS * 200  ({delta, delta*x})
    float* Bmv = ddx + ROWS * 2 * DM;         // ROWS * 300
    float* Cmv = Bmv + ROWS * NS;             // ROWS * 300
    float* yv  = Cmv + ROWS * NS;             // ROWS * 100   (~14.5 MB total)

    k_text<<<ROWS / 4, 256, 0, stream>>>(
        text, tW1, tb1, tg1, tbe1, tW2, tb2, tg2, tbe2,
        sW1, sb1, sW2, sb2, sW3, sb3, ddx, Bmv, Cmv, probe);

    k_scan<<<3200 / 4, 256, 0, stream>>>(ddx, Bmv, Cmv, sA, yv, probe);

    k_head<<<ROWS / 4, 256, 0, stream>>>(yv, cW1, cb1, cW2, cb2, d_out, probe);
}

// Round 6
// 252.644 us; speedup vs baseline: 1.2032x; 1.2032x over previous
//
#include <hip/hip_runtime.h>
#include <hip/hip_bf16.h>

// Simple_6270652252303. Inputs float32 (detector-verified; bf16 insurance path
// kept). Text branch only feeds output.
//   K1 k_text: 4 rows/WAVE (weight float2 -> 8 FMAs), wave-private transposed
//              LDS ([k][4rows] -> broadcast ds_read_b128), no barriers.
//              Outputs: ddx {de,de*x} per d, BC interleaved {B,C} per n.
//   K2 k_scan: wave per 2 d's, lanes over N, depth-2 register prefetch,
//              float2 {B,C} loads, no LDS/barriers.
//   K3 k_head: wave per row -> out.

typedef __hip_bfloat16 bf16;

#define BATCH 64
#define SEQ   63
#define ROWS  (BATCH * SEQ)   // 4032
#define DIN   100
#define H1    128
#define DM    100
#define NS    300

__device__ __forceinline__ float2 up2(unsigned u) {
    float2 r;
    r.x = __uint_as_float(u << 16);
    r.y = __uint_as_float(u & 0xffff0000u);
    return r;
}
template<bool ISB>
__device__ __forceinline__ float LD(const void* p, int i) {
    if (ISB) return __bfloat162float(((const bf16*)p)[i]);
    else     return ((const float*)p)[i];
}
template<bool ISB>
__device__ __forceinline__ float2 LD2(const void* p, int i) {   // elements 2i,2i+1
    if (ISB) return up2(((const unsigned*)p)[i]);
    else     return ((const float2*)p)[i];
}
__device__ __forceinline__ float waveReduceSum(float v) {
#pragma unroll
    for (int off = 32; off > 0; off >>= 1) v += __shfl_xor(v, off, 64);
    return v;
}
__device__ __forceinline__ float lrelu(float x) { return x >= 0.f ? x : 0.01f * x; }
__device__ __forceinline__ float softplusf(float x) {
    return (x > 20.f) ? x : log1pf(__expf(x));
}

// bf16-vs-f32 storage detector (wave-uniform ballot; no LDS, no barrier).
__device__ __forceinline__ bool detect_bf16(const unsigned short* __restrict__ probe) {
    const int l = threadIdx.x & 63;
    const unsigned u0 = probe[l * 2];
    const unsigned u1 = probe[l * 2 + 1];
    const float v0 = fabsf(__uint_as_float(u0 << 16));
    const float v1 = fabsf(__uint_as_float(u1 << 16));
    const bool big = !(v0 < 1000.f) || !(v1 < 1000.f);
    const bool zero_even = (u0 == 0u);
    const unsigned long long mb = __ballot(big);
    const unsigned long long mz = __ballot(zero_even);
    return (mb == 0ULL) && (__popcll(mz) < 32);
}

// ---------------------------------------------------------------------------
// K1: 4 rows per wave, 4 waves/block -> 16 rows/block, grid 252.
// LDS layout transposed: buf[w][k][r], so per-k access is one broadcast b128.
// ---------------------------------------------------------------------------
template<bool ISB>
__device__ __forceinline__ void text_impl(
    const void* __restrict__ text,
    const void* __restrict__ tW1, const void* __restrict__ tb1,
    const void* __restrict__ tg1, const void* __restrict__ tbe1,
    const void* __restrict__ tW2, const void* __restrict__ tb2,
    const void* __restrict__ tg2, const void* __restrict__ tbe2,
    const void* __restrict__ sW1, const void* __restrict__ sb1,
    const void* __restrict__ sW2, const void* __restrict__ sb2,
    const void* __restrict__ sW3, const void* __restrict__ sb3,
    float* __restrict__ ddx, float* __restrict__ BC,
    float (&xb)[4][DIN][4], float (&t1b)[4][H1][4], float (&t2b)[4][DM][4])
{
    const int w    = threadIdx.x >> 6;
    const int lane = threadIdx.x & 63;
    const int base = blockIdx.x * 16 + w * 4;   // rows base..base+3

    if (lane < 50) {                             // stage x rows, transposed
#pragma unroll
        for (int r = 0; r < 4; ++r) {
            const float2 xv = LD2<ISB>(text, (base + r) * 50 + lane);
            xb[w][2 * lane][r]     = xv.x;
            xb[w][2 * lane + 1][r] = xv.y;
        }
    }
    // wave-private: no barrier

    // ---- GEMM1 (100 -> 128): lane covers cols 2*lane, 2*lane+1, 4 rows ----
    const float2 b1v = LD2<ISB>(tb1, lane);
    float ax[4], ay[4];
#pragma unroll
    for (int r = 0; r < 4; ++r) { ax[r] = b1v.x; ay[r] = b1v.y; }
#pragma unroll 4
    for (int k = 0; k < DIN; ++k) {
        const float2 wv = LD2<ISB>(tW1, k * 64 + lane);
        const float4 xv = *(const float4*)&xb[w][k][0];
        ax[0] += xv.x * wv.x; ay[0] += xv.x * wv.y;
        ax[1] += xv.y * wv.x; ay[1] += xv.y * wv.y;
        ax[2] += xv.z * wv.x; ay[2] += xv.z * wv.y;
        ax[3] += xv.w * wv.x; ay[3] += xv.w * wv.y;
    }
    {   // LN(128)+LReLU per row
        const float2 g = LD2<ISB>(tg1, lane), be = LD2<ISB>(tbe1, lane);
#pragma unroll
        for (int r = 0; r < 4; ++r) {
            const float sm = waveReduceSum(ax[r] + ay[r]);
            const float sq = waveReduceSum(ax[r] * ax[r] + ay[r] * ay[r]);
            const float m  = sm * (1.f / 128.f);
            const float rs = rsqrtf(sq * (1.f / 128.f) - m * m + 1e-5f);
            t1b[w][2 * lane][r]     = lrelu((ax[r] - m) * rs * g.x + be.x);
            t1b[w][2 * lane + 1][r] = lrelu((ay[r] - m) * rs * g.y + be.y);
        }
    }

    // ---- GEMM2 (128 -> 100): lanes 0..49 cover cols 2li, 2li+1 ----
    const bool act = lane < 50;
    const int  li  = act ? lane : 0;
    const float2 b2v = LD2<ISB>(tb2, li);
    float cx[4], cy[4];
#pragma unroll
    for (int r = 0; r < 4; ++r) { cx[r] = b2v.x; cy[r] = b2v.y; }
#pragma unroll 4
    for (int k = 0; k < H1; ++k) {
        const float2 wv = LD2<ISB>(tW2, k * 50 + li);
        const float4 tv = *(const float4*)&t1b[w][k][0];
        cx[0] += tv.x * wv.x; cy[0] += tv.x * wv.y;
        cx[1] += tv.y * wv.x; cy[1] += tv.y * wv.y;
        cx[2] += tv.z * wv.x; cy[2] += tv.z * wv.y;
        cx[3] += tv.w * wv.x; cy[3] += tv.w * wv.y;
    }
    {   // LN(100)+LReLU per row
        const float2 g = LD2<ISB>(tg2, li), be = LD2<ISB>(tbe2, li);
#pragma unroll
        for (int r = 0; r < 4; ++r) {
            const float sm = waveReduceSum(act ? cx[r] + cy[r] : 0.f);
            const float sq = waveReduceSum(act ? cx[r] * cx[r] + cy[r] * cy[r] : 0.f);
            const float m  = sm * 0.01f;
            const float rs = rsqrtf(sq * 0.01f - m * m + 1e-5f);
            if (act) {
                t2b[w][2 * lane][r]     = lrelu((cx[r] - m) * rs * g.x + be.x);
                t2b[w][2 * lane + 1][r] = lrelu((cy[r] - m) * rs * g.y + be.y);
            }
        }
    }

    // ---- fused delta(100) + B(300) + C(300) over k<100, 4 rows ----
    const float2 sbv = LD2<ISB>(sb1, li);
    float dlx[4], dly[4];
#pragma unroll
    for (int r = 0; r < 4; ++r) { dlx[r] = sbv.x; dly[r] = sbv.y; }
    int pc[3]; bool pv[3];
    float aBx[3][4], aBy[3][4], aCx[3][4], aCy[3][4];
#pragma unroll
    for (int cc = 0; cc < 3; ++cc) {
        const int p = lane + 64 * cc;
        pv[cc] = p < 150;
        pc[cc] = pv[cc] ? p : 0;
        const float2 bb = LD2<ISB>(sb2, pc[cc]);
        const float2 cb = LD2<ISB>(sb3, pc[cc]);
#pragma unroll
        for (int r = 0; r < 4; ++r) {
            aBx[cc][r] = bb.x; aBy[cc][r] = bb.y;
            aCx[cc][r] = cb.x; aCy[cc][r] = cb.y;
        }
    }
#pragma unroll 2
    for (int k = 0; k < DM; ++k) {
        const float4 tv = *(const float4*)&t2b[w][k][0];
        const float tr[4] = {tv.x, tv.y, tv.z, tv.w};
        const float2 wv = LD2<ISB>(sW1, k * 50 + li);
#pragma unroll
        for (int r = 0; r < 4; ++r) {
            dlx[r] += tr[r] * wv.x; dly[r] += tr[r] * wv.y;
        }
#pragma unroll
        for (int cc = 0; cc < 3; ++cc) {
            const float2 bw = LD2<ISB>(sW2, k * 150 + pc[cc]);
            const float2 cw = LD2<ISB>(sW3, k * 150 + pc[cc]);
#pragma unroll
            for (int r = 0; r < 4; ++r) {
                aBx[cc][r] += tr[r] * bw.x; aBy[cc][r] += tr[r] * bw.y;
                aCx[cc][r] += tr[r] * cw.x; aCy[cc][r] += tr[r] * cw.y;
            }
        }
    }
    if (act) {
#pragma unroll
        for (int r = 0; r < 4; ++r) {
            const float de0 = softplusf(dlx[r]);
            const float de1 = softplusf(dly[r]);
            float4 o;
            o.x = de0; o.y = de0 * t2b[w][2 * lane][r];
            o.z = de1; o.w = de1 * t2b[w][2 * lane + 1][r];
            *(float4*)(ddx + (base + r) * (2 * DM) + 4 * lane) = o;
        }
    }
#pragma unroll
    for (int cc = 0; cc < 3; ++cc) {
        if (pv[cc]) {
#pragma unroll
            for (int r = 0; r < 4; ++r) {
                float4 o;   // {B_2p, C_2p, B_2p+1, C_2p+1}
                o.x = aBx[cc][r]; o.y = aCx[cc][r];
                o.z = aBy[cc][r]; o.w = aCy[cc][r];
                *(float4*)(BC + (base + r) * (2 * NS) + 4 * pc[cc]) = o;
            }
        }
    }
}

__global__ __launch_bounds__(256) void k_text(
    const void* text,
    const void* tW1, const void* tb1, const void* tg1, const void* tbe1,
    const void* tW2, const void* tb2, const void* tg2, const void* tbe2,
    const void* sW1, const void* sb1, const void* sW2, const void* sb2,
    const void* sW3, const void* sb3,
    float* ddx, float* BC, const unsigned short* probe)
{
    __shared__ float xb[4][DIN][4];
    __shared__ float t1b[4][H1][4];
    __shared__ float t2b[4][DM][4];
    if (detect_bf16(probe))
        text_impl<true >(text, tW1, tb1, tg1, tbe1, tW2, tb2, tg2, tbe2,
                         sW1, sb1, sW2, sb2, sW3, sb3, ddx, BC, xb, t1b, t2b);
    else
        text_impl<false>(text, tW1, tb1, tg1, tbe1, tW2, tb2, tg2, tbe2,
                         sW1, sb1, sW2, sb2, sW3, sb3, ddx, BC, xb, t1b, t2b);
}

// ---------------------------------------------------------------------------
// K2: S6 scan. Wave wid: b=wid/50, dp=wid%50 (d0=2dp,d1=2dp+1). Lanes over N.
// Depth-2 register prefetch; {B,C} read as one float2 per n.
// ---------------------------------------------------------------------------
template<bool ISB>
__device__ __forceinline__ void scan_impl(
    const float* __restrict__ ddx, const float* __restrict__ BC,
    const void* __restrict__ sA, float* __restrict__ y)
{
    const int w    = threadIdx.x >> 6;
    const int lane = threadIdx.x & 63;
    const int wid  = blockIdx.x * 4 + w;      // 0..3199
    const int b    = wid / 50;
    const int dp   = wid % 50;
    const int d0   = 2 * dp, d1 = d0 + 1;

    int nc[5]; bool nv[5];
    float A0[5], A1[5], h0[5], h1[5];
#pragma unroll
    for (int c = 0; c < 5; ++c) {
        const int n = lane + 64 * c;
        nv[c] = n < NS;
        nc[c] = nv[c] ? n : 0;
        A0[c] = nv[c] ? LD<ISB>(sA, d0 * NS + nc[c]) : 0.f;
        A1[c] = nv[c] ? LD<ISB>(sA, d1 * NS + nc[c]) : 0.f;
        h0[c] = 0.f; h1[c] = 0.f;
    }

    const float* ddp = ddx + (b * SEQ) * (2 * DM) + 4 * dp;  // {de0,dx0,de1,dx1}
    const float* BCp = BC  + (b * SEQ) * (2 * NS);
    float*       yp  = y   + (b * SEQ) * DM + d0;

    float4 dd0 = *(const float4*)ddp;
    float4 dd1 = *(const float4*)(ddp + 1 * (2 * DM));
    float2 bc0[5], bc1[5];
#pragma unroll
    for (int c = 0; c < 5; ++c) {
        bc0[c] = nv[c] ? *(const float2*)(BCp + 2 * nc[c]) : make_float2(0.f, 0.f);
        bc1[c] = nv[c] ? *(const float2*)(BCp + 2 * NS + 2 * nc[c]) : make_float2(0.f, 0.f);
    }

    for (int l = 0; l < SEQ; ++l) {
        float4 dd2 = dd1;
        float2 bc2[5];
#pragma unroll
        for (int c = 0; c < 5; ++c) bc2[c] = bc1[c];
        if (l + 2 < SEQ) {
            dd2 = *(const float4*)(ddp + (l + 2) * (2 * DM));
#pragma unroll
            for (int c = 0; c < 5; ++c)
                bc2[c] = nv[c] ? *(const float2*)(BCp + (l + 2) * (2 * NS) + 2 * nc[c])
                               : make_float2(0.f, 0.f);
        }
        float acc0 = 0.f, acc1 = 0.f;
#pragma unroll
        for (int c = 0; c < 5; ++c) {
            h0[c] = __expf(dd0.x * A0[c]) * h0[c] + dd0.y * bc0[c].x;
            acc0 += bc0[c].y * h0[c];
            h1[c] = __expf(dd0.z * A1[c]) * h1[c] + dd0.w * bc0[c].x;
            acc1 += bc0[c].y * h1[c];
        }
        acc0 = waveReduceSum(acc0);
        acc1 = waveReduceSum(acc1);
        if (lane == 0) *(float2*)(yp + l * DM) = make_float2(acc0, acc1);
        dd0 = dd1; dd1 = dd2;
#pragma unroll
        for (int c = 0; c < 5; ++c) { bc0[c] = bc1[c]; bc1[c] = bc2[c]; }
    }
}

__global__ __launch_bounds__(256) void k_scan(
    const float* ddx, const float* BC, const void* sA, float* y,
    const unsigned short* probe)
{
    if (detect_bf16(probe)) scan_impl<true >(ddx, BC, sA, y);
    else                    scan_impl<false>(ddx, BC, sA, y);
}

// ---------------------------------------------------------------------------
// K3: head. Wave per row, wave-private LDS, no barriers.
// ---------------------------------------------------------------------------
template<bool ISB>
__device__ __forceinline__ void head_impl(
    const float* __restrict__ y,
    const void* __restrict__ cW1, const void* __restrict__ cb1,
    const void* __restrict__ cW2, const void* __restrict__ cb2,
    void* __restrict__ outp, float (&ybuf)[4][100])
{
    const int w    = threadIdx.x >> 6;
    const int lane = threadIdx.x & 63;
    const int row  = blockIdx.x * 4 + w;

    ybuf[w][lane] = y[row * DM + lane];
    if (lane < DM - 64) ybuf[w][lane + 64] = y[row * DM + lane + 64];

    const bool vi = lane < 50;
    const int  i  = vi ? lane : 0;
    float o1 = LD<ISB>(cb1, i);
#pragma unroll 10
    for (int k = 0; k < DM; ++k) o1 += ybuf[w][k] * LD<ISB>(cW1, k * 50 + i);

    float p0 = vi ? o1 * LD<ISB>(cW2, i * 2 + 0) : 0.f;
    float p1 = vi ? o1 * LD<ISB>(cW2, i * 2 + 1) : 0.f;
    p0 = waveReduceSum(p0);
    p1 = waveReduceSum(p1);
    if (lane == 0) {
        const float r0 = p0 + LD<ISB>(cb2, 0);
        const float r1 = p1 + LD<ISB>(cb2, 1);
        if (ISB) {
            ((bf16*)outp)[row * 2 + 0] = __float2bfloat16(r0);
            ((bf16*)outp)[row * 2 + 1] = __float2bfloat16(r1);
        } else {
            *(float2*)((float*)outp + row * 2) = make_float2(r0, r1);
        }
    }
}

__global__ __launch_bounds__(256) void k_head(
    const float* y, const void* cW1, const void* cb1,
    const void* cW2, const void* cb2, void* outp, const unsigned short* probe)
{
    __shared__ float ybuf[4][100];
    if (detect_bf16(probe)) head_impl<true >(y, cW1, cb1, cW2, cb2, outp, ybuf);
    else                    head_impl<false>(y, cW1, cb1, cW2, cb2, outp, ybuf);
}

// ---------------------------------------------------------------------------
extern "C" void kernel_launch(void* const* d_in, const int* in_sizes, int n_in,
                              void* d_out, int out_size, void* d_ws, size_t ws_size,
                              hipStream_t stream)
{
    const void* text = d_in[0];
    const void* tW1  = d_in[3];
    const void* tb1  = d_in[4];
    const void* tg1  = d_in[5];
    const void* tbe1 = d_in[6];
    const void* tW2  = d_in[7];
    const void* tb2  = d_in[8];
    const void* tg2  = d_in[9];
    const void* tbe2 = d_in[10];
    const void* sW1  = d_in[11];
    const void* sb1  = d_in[12];
    const void* sW2  = d_in[13];
    const void* sb2  = d_in[14];
    const void* sW3  = d_in[15];
    const void* sb3  = d_in[16];
    const void* sA   = d_in[17];
    const void* cW1  = d_in[34];
    const void* cb1  = d_in[35];
    const void* cW2  = d_in[36];
    const void* cb2  = d_in[37];
    const unsigned short* probe = (const unsigned short*)d_in[3];

    float* ws  = (float*)d_ws;
    float* ddx = ws;                          // ROWS * 200  ({de, de*x} pairs)
    float* BCv = ddx + ROWS * 2 * DM;         // ROWS * 600  ({B,C} interleaved)
    float* yv  = BCv + ROWS * 2 * NS;         // ROWS * 100   (~14.5 MB total)

    k_text<<<ROWS / 16, 256, 0, stream>>>(
        text, tW1, tb1, tg1, tbe1, tW2, tb2, tg2, tbe2,
        sW1, sb1, sW2, sb2, sW3, sb3, ddx, BCv, probe);

    k_scan<<<3200 / 4, 256, 0, stream>>>(ddx, BCv, sA, yv, probe);

    k_head<<<ROWS / 4, 256, 0, stream>>>(yv, cW1, cb1, cW2, cb2, d_out, probe);
}

// Round 7
// 242.105 us; speedup vs baseline: 1.2556x; 1.0435x over previous
//
#include <hip/hip_runtime.h>
#include <hip/hip_bf16.h>

// Simple_6270652252303. Inputs float32 (detector-verified; bf16 path kept as
// insurance). Text branch only feeds output.
//   K1 k_text: 4 rows/wave, wave-private transposed LDS, no barriers (R6).
//   K2 k_scan: wave per 2 d's, lanes over N. Chunked reduction: per-step
//              partials ds_write'd to wave-private LDS; every 16 steps one
//              PARALLEL chunk-reduce (32 pairs x 2 lanes). Removes the
//              12-serial-shfl/step chain (~1400 cy/step) from the scan.
//   K3 k_head: wave per row; dual-chain (interleaved) final reduce.

typedef __hip_bfloat16 bf16;

#define BATCH 64
#define SEQ   63
#define ROWS  (BATCH * SEQ)   // 4032
#define DIN   100
#define H1    128
#define DM    100
#define NS    300

__device__ __forceinline__ float2 up2(unsigned u) {
    float2 r;
    r.x = __uint_as_float(u << 16);
    r.y = __uint_as_float(u & 0xffff0000u);
    return r;
}
template<bool ISB>
__device__ __forceinline__ float LD(const void* p, int i) {
    if (ISB) return __bfloat162float(((const bf16*)p)[i]);
    else     return ((const float*)p)[i];
}
template<bool ISB>
__device__ __forceinline__ float2 LD2(const void* p, int i) {   // elements 2i,2i+1
    if (ISB) return up2(((const unsigned*)p)[i]);
    else     return ((const float2*)p)[i];
}
__device__ __forceinline__ float waveReduceSum(float v) {
#pragma unroll
    for (int off = 32; off > 0; off >>= 1) v += __shfl_xor(v, off, 64);
    return v;
}
// two independent reduction chains, interleaved so their ~120cy DS latencies overlap
__device__ __forceinline__ float2 waveReduceSum2(float2 v) {
#pragma unroll
    for (int off = 32; off > 0; off >>= 1) {
        const float ax = __shfl_xor(v.x, off, 64);
        const float ay = __shfl_xor(v.y, off, 64);
        v.x += ax; v.y += ay;
    }
    return v;
}
__device__ __forceinline__ float lrelu(float x) { return x >= 0.f ? x : 0.01f * x; }
__device__ __forceinline__ float softplusf(float x) {
    return (x > 20.f) ? x : log1pf(__expf(x));
}

// bf16-vs-f32 storage detector (wave-uniform ballot; no LDS, no barrier).
__device__ __forceinline__ bool detect_bf16(const unsigned short* __restrict__ probe) {
    const int l = threadIdx.x & 63;
    const unsigned u0 = probe[l * 2];
    const unsigned u1 = probe[l * 2 + 1];
    const float v0 = fabsf(__uint_as_float(u0 << 16));
    const float v1 = fabsf(__uint_as_float(u1 << 16));
    const bool big = !(v0 < 1000.f) || !(v1 < 1000.f);
    const bool zero_even = (u0 == 0u);
    const unsigned long long mb = __ballot(big);
    const unsigned long long mz = __ballot(zero_even);
    return (mb == 0ULL) && (__popcll(mz) < 32);
}

// ---------------------------------------------------------------------------
// K1: 4 rows per wave, 4 waves/block -> 16 rows/block, grid 252.
// LDS transposed buf[w][k][r] -> per-k access is one broadcast b128.
// ---------------------------------------------------------------------------
template<bool ISB>
__device__ __forceinline__ void text_impl(
    const void* __restrict__ text,
    const void* __restrict__ tW1, const void* __restrict__ tb1,
    const void* __restrict__ tg1, const void* __restrict__ tbe1,
    const void* __restrict__ tW2, const void* __restrict__ tb2,
    const void* __restrict__ tg2, const void* __restrict__ tbe2,
    const void* __restrict__ sW1, const void* __restrict__ sb1,
    const void* __restrict__ sW2, const void* __restrict__ sb2,
    const void* __restrict__ sW3, const void* __restrict__ sb3,
    float* __restrict__ ddx, float* __restrict__ BC,
    float (&xb)[4][DIN][4], float (&t1b)[4][H1][4], float (&t2b)[4][DM][4])
{
    const int w    = threadIdx.x >> 6;
    const int lane = threadIdx.x & 63;
    const int base = blockIdx.x * 16 + w * 4;   // rows base..base+3

    if (lane < 50) {
#pragma unroll
        for (int r = 0; r < 4; ++r) {
            const float2 xv = LD2<ISB>(text, (base + r) * 50 + lane);
            xb[w][2 * lane][r]     = xv.x;
            xb[w][2 * lane + 1][r] = xv.y;
        }
    }
    // wave-private: no barrier

    // ---- GEMM1 (100 -> 128) ----
    const float2 b1v = LD2<ISB>(tb1, lane);
    float ax[4], ay[4];
#pragma unroll
    for (int r = 0; r < 4; ++r) { ax[r] = b1v.x; ay[r] = b1v.y; }
#pragma unroll 4
    for (int k = 0; k < DIN; ++k) {
        const float2 wv = LD2<ISB>(tW1, k * 64 + lane);
        const float4 xv = *(const float4*)&xb[w][k][0];
        ax[0] += xv.x * wv.x; ay[0] += xv.x * wv.y;
        ax[1] += xv.y * wv.x; ay[1] += xv.y * wv.y;
        ax[2] += xv.z * wv.x; ay[2] += xv.z * wv.y;
        ax[3] += xv.w * wv.x; ay[3] += xv.w * wv.y;
    }
    {   // LN(128)+LReLU per row (dual-chain reduce)
        const float2 g = LD2<ISB>(tg1, lane), be = LD2<ISB>(tbe1, lane);
#pragma unroll
        for (int r = 0; r < 4; ++r) {
            float2 red = waveReduceSum2(make_float2(ax[r] + ay[r],
                                                    ax[r] * ax[r] + ay[r] * ay[r]));
            const float m  = red.x * (1.f / 128.f);
            const float rs = rsqrtf(red.y * (1.f / 128.f) - m * m + 1e-5f);
            t1b[w][2 * lane][r]     = lrelu((ax[r] - m) * rs * g.x + be.x);
            t1b[w][2 * lane + 1][r] = lrelu((ay[r] - m) * rs * g.y + be.y);
        }
    }

    // ---- GEMM2 (128 -> 100) ----
    const bool act = lane < 50;
    const int  li  = act ? lane : 0;
    const float2 b2v = LD2<ISB>(tb2, li);
    float cx[4], cy[4];
#pragma unroll
    for (int r = 0; r < 4; ++r) { cx[r] = b2v.x; cy[r] = b2v.y; }
#pragma unroll 4
    for (int k = 0; k < H1; ++k) {
        const float2 wv = LD2<ISB>(tW2, k * 50 + li);
        const float4 tv = *(const float4*)&t1b[w][k][0];
        cx[0] += tv.x * wv.x; cy[0] += tv.x * wv.y;
        cx[1] += tv.y * wv.x; cy[1] += tv.y * wv.y;
        cx[2] += tv.z * wv.x; cy[2] += tv.z * wv.y;
        cx[3] += tv.w * wv.x; cy[3] += tv.w * wv.y;
    }
    {   // LN(100)+LReLU per row
        const float2 g = LD2<ISB>(tg2, li), be = LD2<ISB>(tbe2, li);
#pragma unroll
        for (int r = 0; r < 4; ++r) {
            float2 red = waveReduceSum2(act ? make_float2(cx[r] + cy[r],
                                                          cx[r] * cx[r] + cy[r] * cy[r])
                                            : make_float2(0.f, 0.f));
            const float m  = red.x * 0.01f;
            const float rs = rsqrtf(red.y * 0.01f - m * m + 1e-5f);
            if (act) {
                t2b[w][2 * lane][r]     = lrelu((cx[r] - m) * rs * g.x + be.x);
                t2b[w][2 * lane + 1][r] = lrelu((cy[r] - m) * rs * g.y + be.y);
            }
        }
    }

    // ---- fused delta(100) + B(300) + C(300) over k<100, 4 rows ----
    const float2 sbv = LD2<ISB>(sb1, li);
    float dlx[4], dly[4];
#pragma unroll
    for (int r = 0; r < 4; ++r) { dlx[r] = sbv.x; dly[r] = sbv.y; }
    int pc[3]; bool pv[3];
    float aBx[3][4], aBy[3][4], aCx[3][4], aCy[3][4];
#pragma unroll
    for (int cc = 0; cc < 3; ++cc) {
        const int p = lane + 64 * cc;
        pv[cc] = p < 150;
        pc[cc] = pv[cc] ? p : 0;
        const float2 bb = LD2<ISB>(sb2, pc[cc]);
        const float2 cb = LD2<ISB>(sb3, pc[cc]);
#pragma unroll
        for (int r = 0; r < 4; ++r) {
            aBx[cc][r] = bb.x; aBy[cc][r] = bb.y;
            aCx[cc][r] = cb.x; aCy[cc][r] = cb.y;
        }
    }
#pragma unroll 2
    for (int k = 0; k < DM; ++k) {
        const float4 tv = *(const float4*)&t2b[w][k][0];
        const float tr[4] = {tv.x, tv.y, tv.z, tv.w};
        const float2 wv = LD2<ISB>(sW1, k * 50 + li);
#pragma unroll
        for (int r = 0; r < 4; ++r) {
            dlx[r] += tr[r] * wv.x; dly[r] += tr[r] * wv.y;
        }
#pragma unroll
        for (int cc = 0; cc < 3; ++cc) {
            const float2 bw = LD2<ISB>(sW2, k * 150 + pc[cc]);
            const float2 cw = LD2<ISB>(sW3, k * 150 + pc[cc]);
#pragma unroll
            for (int r = 0; r < 4; ++r) {
                aBx[cc][r] += tr[r] * bw.x; aBy[cc][r] += tr[r] * bw.y;
                aCx[cc][r] += tr[r] * cw.x; aCy[cc][r] += tr[r] * cw.y;
            }
        }
    }
    if (act) {
#pragma unroll
        for (int r = 0; r < 4; ++r) {
            const float de0 = softplusf(dlx[r]);
            const float de1 = softplusf(dly[r]);
            float4 o;
            o.x = de0; o.y = de0 * t2b[w][2 * lane][r];
            o.z = de1; o.w = de1 * t2b[w][2 * lane + 1][r];
            *(float4*)(ddx + (base + r) * (2 * DM) + 4 * lane) = o;
        }
    }
#pragma unroll
    for (int cc = 0; cc < 3; ++cc) {
        if (pv[cc]) {
#pragma unroll
            for (int r = 0; r < 4; ++r) {
                float4 o;   // {B_2p, C_2p, B_2p+1, C_2p+1}
                o.x = aBx[cc][r]; o.y = aCx[cc][r];
                o.z = aBy[cc][r]; o.w = aCy[cc][r];
                *(float4*)(BC + (base + r) * (2 * NS) + 4 * pc[cc]) = o;
            }
        }
    }
}

__global__ __launch_bounds__(256) void k_text(
    const void* text,
    const void* tW1, const void* tb1, const void* tg1, const void* tbe1,
    const void* tW2, const void* tb2, const void* tg2, const void* tbe2,
    const void* sW1, const void* sb1, const void* sW2, const void* sb2,
    const void* sW3, const void* sb3,
    float* ddx, float* BC, const unsigned short* probe)
{
    __shared__ float xb[4][DIN][4];
    __shared__ float t1b[4][H1][4];
    __shared__ float t2b[4][DM][4];
    if (detect_bf16(probe))
        text_impl<true >(text, tW1, tb1, tg1, tbe1, tW2, tb2, tg2, tbe2,
                         sW1, sb1, sW2, sb2, sW3, sb3, ddx, BC, xb, t1b, t2b);
    else
        text_impl<false>(text, tW1, tb1, tg1, tbe1, tW2, tb2, tg2, tbe2,
                         sW1, sb1, sW2, sb2, sW3, sb3, ddx, BC, xb, t1b, t2b);
}

// ---------------------------------------------------------------------------
// K2: S6 scan with chunked parallel reduction.
// Wave wid: b=wid/50, dp=wid%50 (d0=2dp, d1=2dp+1). Lanes over N (5 each).
// Per step: lane-local h update + 2 ds_write of partials (no barrier — DS ops
// are program-ordered within a wave). Every 16 steps: parallel chunk-reduce
// (pair p=lane>>1 -> (step,a); each lane sums 32 floats via 8 b128 reads;
// shfl_xor(1) combines halves; one scattered y store per pair).
// ---------------------------------------------------------------------------
template<bool ISB>
__device__ __forceinline__ void scan_impl(
    const float* __restrict__ ddx, const float* __restrict__ BC,
    const void* __restrict__ sA, float* __restrict__ y,
    float (&sacc)[4][16][2][68])
{
    const int w    = threadIdx.x >> 6;
    const int lane = threadIdx.x & 63;
    const int wid  = blockIdx.x * 4 + w;      // 0..3199
    const int b    = wid / 50;
    const int dp   = wid % 50;
    const int d0   = 2 * dp, d1 = d0 + 1;

    int nc[5]; bool nv[5];
    float A0[5], A1[5], h0[5], h1[5];
#pragma unroll
    for (int c = 0; c < 5; ++c) {
        const int n = lane + 64 * c;
        nv[c] = n < NS;
        nc[c] = nv[c] ? n : 0;
        A0[c] = nv[c] ? LD<ISB>(sA, d0 * NS + nc[c]) : 0.f;
        A1[c] = nv[c] ? LD<ISB>(sA, d1 * NS + nc[c]) : 0.f;
        h0[c] = 0.f; h1[c] = 0.f;
    }

    const float* ddp = ddx + (b * SEQ) * (2 * DM) + 4 * dp;  // {de0,dx0,de1,dx1}
    const float* BCp = BC  + (b * SEQ) * (2 * NS);
    float*       yp  = y   + (b * SEQ) * DM + d0;

    // register prefetch pipeline, depth 3 (63 = 3*21)
    float4 pdd[3];
    float2 pbc[3][5];
#pragma unroll
    for (int j = 0; j < 3; ++j) {
        pdd[j] = *(const float4*)(ddp + j * (2 * DM));
#pragma unroll
        for (int c = 0; c < 5; ++c)
            pbc[j][c] = nv[c] ? *(const float2*)(BCp + j * (2 * NS) + 2 * nc[c])
                              : make_float2(0.f, 0.f);
    }

    // chunk-reduce lane roles
    const int pr = lane >> 1;        // pair 0..31
    const int hh = lane & 1;         // which half of 64 partials
    const int sa = pr & 15;          // step-in-chunk
    const int aa = pr >> 4;          // which acc (d0 or d1)

#pragma unroll 3
    for (int l = 0; l < SEQ; ++l) {
        const int bi = l % 3;
        const float4 dd = pdd[bi];
        float2 bc[5];
#pragma unroll
        for (int c = 0; c < 5; ++c) bc[c] = pbc[bi][c];
        if (l + 3 < SEQ) {           // refill this slot for step l+3
            pdd[bi] = *(const float4*)(ddp + (l + 3) * (2 * DM));
#pragma unroll
            for (int c = 0; c < 5; ++c)
                pbc[bi][c] = nv[c] ? *(const float2*)(BCp + (l + 3) * (2 * NS) + 2 * nc[c])
                                   : make_float2(0.f, 0.f);
        }

        float a0 = 0.f, a1 = 0.f;
#pragma unroll
        for (int c = 0; c < 5; ++c) {
            h0[c] = __expf(dd.x * A0[c]) * h0[c] + dd.y * bc[c].x;
            a0 += bc[c].y * h0[c];
            h1[c] = __expf(dd.z * A1[c]) * h1[c] + dd.w * bc[c].x;
            a1 += bc[c].y * h1[c];
        }
        const int s = l & 15;
        sacc[w][s][0][lane] = a0;    // stride-1 -> conflict-free, fire-and-forget
        sacc[w][s][1][lane] = a1;

        if (s == 15 || l == SEQ - 1) {
            const int l0 = l & ~15;
            const int cs = l - l0 + 1;
            float sum = 0.f;
            if (sa < cs) {
                const float* rowp = &sacc[w][sa][aa][hh * 32];
#pragma unroll
                for (int i = 0; i < 8; ++i) {
                    const float4 v = *(const float4*)(rowp + 4 * i);
                    sum += v.x + v.y + v.z + v.w;
                }
            }
            sum += __shfl_xor(sum, 1, 64);
            if (hh == 0 && sa < cs) yp[(l0 + sa) * DM + aa] = sum;
        }
    }
}

__global__ __launch_bounds__(256) void k_scan(
    const float* ddx, const float* BC, const void* sA, float* y,
    const unsigned short* probe)
{
    __shared__ __align__(16) float sacc[4][16][2][68];   // ~34.8 KB
    if (detect_bf16(probe)) scan_impl<true >(ddx, BC, sA, y, sacc);
    else                    scan_impl<false>(ddx, BC, sA, y, sacc);
}

// ---------------------------------------------------------------------------
// K3: head. Wave per row, wave-private LDS, dual-chain final reduce.
// ---------------------------------------------------------------------------
template<bool ISB>
__device__ __forceinline__ void head_impl(
    const float* __restrict__ y,
    const void* __restrict__ cW1, const void* __restrict__ cb1,
    const void* __restrict__ cW2, const void* __restrict__ cb2,
    void* __restrict__ outp, float (&ybuf)[4][100])
{
    const int w    = threadIdx.x >> 6;
    const int lane = threadIdx.x & 63;
    const int row  = blockIdx.x * 4 + w;

    ybuf[w][lane] = y[row * DM + lane];
    if (lane < DM - 64) ybuf[w][lane + 64] = y[row * DM + lane + 64];

    const bool vi = lane < 50;
    const int  i  = vi ? lane : 0;
    float o1 = LD<ISB>(cb1, i);
#pragma unroll 10
    for (int k = 0; k < DM; ++k) o1 += ybuf[w][k] * LD<ISB>(cW1, k * 50 + i);

    float2 p;
    p.x = vi ? o1 * LD<ISB>(cW2, i * 2 + 0) : 0.f;
    p.y = vi ? o1 * LD<ISB>(cW2, i * 2 + 1) : 0.f;
    p = waveReduceSum2(p);
    if (lane == 0) {
        const float r0 = p.x + LD<ISB>(cb2, 0);
        const float r1 = p.y + LD<ISB>(cb2, 1);
        if (ISB) {
            ((bf16*)outp)[row * 2 + 0] = __float2bfloat16(r0);
            ((bf16*)outp)[row * 2 + 1] = __float2bfloat16(r1);
        } else {
            *(float2*)((float*)outp + row * 2) = make_float2(r0, r1);
        }
    }
}

__global__ __launch_bounds__(256) void k_head(
    const float* y, const void* cW1, const void* cb1,
    const void* cW2, const void* cb2, void* outp, const unsigned short* probe)
{
    __shared__ float ybuf[4][100];
    if (detect_bf16(probe)) head_impl<true >(y, cW1, cb1, cW2, cb2, outp, ybuf);
    else                    head_impl<false>(y, cW1, cb1, cW2, cb2, outp, ybuf);
}

// ---------------------------------------------------------------------------
extern "C" void kernel_launch(void* const* d_in, const int* in_sizes, int n_in,
                              void* d_out, int out_size, void* d_ws, size_t ws_size,
                              hipStream_t stream)
{
    const void* text = d_in[0];
    const void* tW1  = d_in[3];
    const void* tb1  = d_in[4];
    const void* tg1  = d_in[5];
    const void* tbe1 = d_in[6];
    const void* tW2  = d_in[7];
    const void* tb2  = d_in[8];
    const void* tg2  = d_in[9];
    const void* tbe2 = d_in[10];
    const void* sW1  = d_in[11];
    const void* sb1  = d_in[12];
    const void* sW2  = d_in[13];
    const void* sb2  = d_in[14];
    const void* sW3  = d_in[15];
    const void* sb3  = d_in[16];
    const void* sA   = d_in[17];
    const void* cW1  = d_in[34];
    const void* cb1  = d_in[35];
    const void* cW2  = d_in[36];
    const void* cb2  = d_in[37];
    const unsigned short* probe = (const unsigned short*)d_in[3];

    float* ws  = (float*)d_ws;
    float* ddx = ws;                          // ROWS * 200  ({de, de*x} pairs)
    float* BCv = ddx + ROWS * 2 * DM;         // ROWS * 600  ({B,C} interleaved)
    float* yv  = BCv + ROWS * 2 * NS;         // ROWS * 100   (~14.5 MB total)

    k_text<<<ROWS / 16, 256, 0, stream>>>(
        text, tW1, tb1, tg1, tbe1, tW2, tb2, tg2, tbe2,
        sW1, sb1, sW2, sb2, sW3, sb3, ddx, BCv, probe);

    k_scan<<<3200 / 4, 256, 0, stream>>>(ddx, BCv, sA, yv, probe);

    k_head<<<ROWS / 4, 256, 0, stream>>>(yv, cW1, cb1, cW2, cb2, d_out, probe);
}